// Round 3
// baseline (578.820 us; speedup 1.0000x reference)
//
#include <hip/hip_runtime.h>
#include <stdint.h>

// MultiHeadAttention_62766652064333: DM=512 H=8 B=8 SQ=SK=1024. f32 I/O, int32 mask.
// v4: fused attention kernel (scores+softmax+att-write+Y in one launch).
// Pipeline (4 launches):
//   prep_w:        Wq^T, Wk^T bf16; Wv plain bf16; Wsum^T bf16; bvs = bv@Wsum
//   prep_qkv_wct:  Q,K,V f32->bf16 (6144 blks) + Wc^T = (Wv@Wsum)^T GEMM (16 blks)
//   gemm_qkvv:     Qlb = Qb@Wqt^T+bq, Klb = Kb@Wkt^T+bk (mode0), Vwt = (Vb@Wct^T+bvs)^T (mode1)
//   fused_attn:    per block: 16 q-rows x full SK. S = Qlb@Klb^T*isc + mask in REGISTERS
//                  (K/V B-frags read direct from global -- L2-resident, no LDS staging),
//                  exact softmax (shfl + tiny LDS cross-wave), att f32 x8 slots written
//                  fire-and-forget, att bf16 -> LDS[16][1032] (padded, conflict-free),
//                  PV: Y = att@Vwt^T + bl.
// Math: Y = att@(Vb@(Wv@Wsum)) + (bv@Wsum) + bl; att rows sum to 1 so bvs folds exactly.

typedef unsigned short u16;
typedef __attribute__((ext_vector_type(8))) short bf16x8;        // MFMA A/B frag
typedef __attribute__((ext_vector_type(8))) unsigned short u16x8;
typedef __attribute__((ext_vector_type(4))) unsigned short u16x4;
typedef __attribute__((ext_vector_type(4))) float f32x4;         // MFMA C/D frag

__device__ __forceinline__ u16 f2bf(float f) {
    union { float f; unsigned int u; } v; v.f = f;
    v.u += 0x7fffu + ((v.u >> 16) & 1u);   // round-to-nearest-even
    return (u16)(v.u >> 16);
}

__device__ __forceinline__ void gld16(const u16* g, u16* l) {
#if __has_builtin(__builtin_amdgcn_global_load_lds)
    __builtin_amdgcn_global_load_lds(
        (const __attribute__((address_space(1))) void*)g,
        (__attribute__((address_space(3))) void*)l, 16, 0, 0);
#else
    *(uint4*)l = *(const uint4*)g;
#endif
}

// ---- shared TN GEMM core: acc[4][4] (+=) A[m0..m0+128, :] @ B[n0..n0+128, :]^T ----
__device__ __forceinline__ void gemm_core(
    const u16* __restrict__ Ab, const u16* __restrict__ Bb,
    int K, int lda, int ldb, int m0, int n0, int t,
    u16 (*As)[32], u16 (*Bs)[32], f32x4 acc[4][4])
{
    const int lane = t & 63;
    const int wm = ((t >> 6) & 1) * 64;
    const int wn = (t >> 7) * 64;
    const int sr = t >> 2, sc = (t & 3) * 8;
    const int fr = lane & 15, fk = (lane >> 4) * 8;

    for (int k0 = 0; k0 < K; k0 += 32) {
        const u16* ap = Ab + (long)(m0 + sr) * lda + (k0 + sc);
        const u16* bp = Bb + (long)(n0 + sr) * ldb + (k0 + sc);
        gld16(ap,             &As[sr][sc]);
        gld16(ap + 64L * lda, &As[sr + 64][sc]);
        gld16(bp,             &Bs[sr][sc]);
        gld16(bp + 64L * ldb, &Bs[sr + 64][sc]);
        __syncthreads();

        bf16x8 af[4], bfv[4];
        #pragma unroll
        for (int i = 0; i < 4; i++) af[i]  = *(const bf16x8*)&As[wm + i*16 + fr][fk];
        #pragma unroll
        for (int j = 0; j < 4; j++) bfv[j] = *(const bf16x8*)&Bs[wn + j*16 + fr][fk];
        #pragma unroll
        for (int i = 0; i < 4; i++)
            #pragma unroll
            for (int j = 0; j < 4; j++)
                acc[i][j] = __builtin_amdgcn_mfma_f32_16x16x32_bf16(af[i], bfv[j], acc[i][j], 0, 0, 0);
        __syncthreads();
    }
}

// mode 0: bf16 C row-major (+bias[col]).  mode 1: bf16 C^T (+bias[col]; C[col*ldc+row]).
__device__ __forceinline__ void gemm_epilogue(
    int mode, void* Cv, const float* bias,
    float scale, int ldc, int m0, int n0, int t, f32x4 acc[4][4])
{
    const int lane = t & 63;
    const int wm = ((t >> 6) & 1) * 64;
    const int wn = (t >> 7) * 64;
    const int cl = lane & 15, rl = (lane >> 4) * 4;

    float badd[4];
    #pragma unroll
    for (int j = 0; j < 4; j++) {
        int col = n0 + wn + j * 16 + cl;
        badd[j] = bias ? bias[col] : 0.f;
    }

    if (mode == 1) {
        u16* C = (u16*)Cv;
        #pragma unroll
        for (int i = 0; i < 4; i++)
            #pragma unroll
            for (int r = 0; r < 4; r++) {
                long row = m0 + wm + i * 16 + rl + r;
                #pragma unroll
                for (int j = 0; j < 4; j++)
                    C[(long)(n0 + wn + j * 16 + cl) * ldc + row] =
                        f2bf(acc[i][j][r] * scale + badd[j]);
            }
    } else {
        u16* C = (u16*)Cv;
        #pragma unroll
        for (int i = 0; i < 4; i++)
            #pragma unroll
            for (int r = 0; r < 4; r++) {
                u16* crow = C + (long)(m0 + wm + i * 16 + rl + r) * ldc;
                #pragma unroll
                for (int j = 0; j < 4; j++)
                    crow[n0 + wn + j * 16 + cl] = f2bf(acc[i][j][r] * scale + badd[j]);
            }
    }
}

// Merged projections: grid (8,4,24). z/8: 0 -> Qlb, 1 -> Klb, 2 -> Vwt (transposed out).
__global__ __launch_bounds__(256, 2)
void gemm_qkvv(const u16* __restrict__ Qb, const u16* __restrict__ Kb,
               const u16* __restrict__ Vb, const u16* __restrict__ Wqt,
               const u16* __restrict__ Wkt, const u16* __restrict__ Wct,
               u16* __restrict__ Qlb, u16* __restrict__ Klb, u16* __restrict__ Vwt,
               const float* __restrict__ bq, const float* __restrict__ bk,
               const float* __restrict__ bvs)
{
    __shared__ __align__(16) u16 As[128][32];
    __shared__ __align__(16) u16 Bs[128][32];
    const int z = blockIdx.z, seg = z >> 3, b = z & 7;
    const int m0 = blockIdx.x * 128, n0 = blockIdx.y * 128;
    const int t = threadIdx.x;
    const long sQ = 524288L;

    const u16* A; const u16* B; u16* C; const float* bias; int ldc, mode;
    if (seg == 0)      { A = Qb + b * sQ; B = Wqt; C = Qlb + b * sQ; bias = bq;  ldc = 512;  mode = 0; }
    else if (seg == 1) { A = Kb + b * sQ; B = Wkt; C = Klb + b * sQ; bias = bk;  ldc = 512;  mode = 0; }
    else               { A = Vb + b * sQ; B = Wct; C = Vwt + b * sQ; bias = bvs; ldc = 1024; mode = 1; }

    f32x4 acc[4][4];
    #pragma unroll
    for (int i = 0; i < 4; i++)
        #pragma unroll
        for (int j = 0; j < 4; j++) acc[i][j] = (f32x4){0.f, 0.f, 0.f, 0.f};

    gemm_core(A, B, 512, 512, 512, m0, n0, t, As, Bs, acc);
    gemm_epilogue(mode, C, bias, 1.f, ldc, m0, n0, t, acc);
}

// Prep weights + bvs tail blocks.
__global__ __launch_bounds__(256)
void prep_w(const float* __restrict__ Wq, const float* __restrict__ Wk,
            const float* __restrict__ Wv, const float* __restrict__ Wl,
            const float* __restrict__ bv,
            u16* __restrict__ Wqt, u16* __restrict__ Wkt,
            u16* __restrict__ Wvb, u16* __restrict__ Wst, float* __restrict__ bvs)
{
    const int bx = blockIdx.x;
    if (bx >= 4096) {
        int n = (bx - 4096) * 256 + threadIdx.x;          // 0..511
        if (n < 512) {
            float acc = 0.f;
            for (int k = 0; k < 512; k++) {
                float bvk = bv[k];
                if (bvk != 0.f) {
                    float s = 0.f;
                    #pragma unroll
                    for (int h = 0; h < 8; h++) s += Wl[((long)h * 512 + k) * 512 + n];
                    acc += bvk * s;
                }
            }
            bvs[n] = acc;
        }
        return;
    }
    long id = (long)bx * 256 + threadIdx.x;               // < 1048576
    int seg = (int)(id >> 18);
    long j = id & 262143L;
    int n = (int)(j & 511), k = (int)(j >> 9);
    if (seg == 0) {
        Wqt[(long)n * 512 + k] = f2bf(Wq[(long)k * 512 + n]);
    } else if (seg == 1) {
        Wkt[(long)n * 512 + k] = f2bf(Wk[(long)k * 512 + n]);
    } else if (seg == 2) {
        Wvb[j] = f2bf(Wv[j]);
    } else {
        float s = 0.f;
        #pragma unroll
        for (int h = 0; h < 8; h++) s += Wl[((long)h * 512 + k) * 512 + n];
        Wst[(long)n * 512 + k] = f2bf(s);
    }
}

// Q,K,V f32->bf16 (blocks 0..6143) + Wc^T GEMM (blocks 6144..6159).
__global__ __launch_bounds__(256, 2)
void prep_qkv_wct(const float* __restrict__ Q, const float* __restrict__ K,
                  const float* __restrict__ V, u16* __restrict__ Qb,
                  u16* __restrict__ Kb, u16* __restrict__ Vb,
                  const u16* __restrict__ Wvb, const u16* __restrict__ Wst,
                  u16* __restrict__ Wct)
{
    __shared__ __align__(16) u16 As[128][32];
    __shared__ __align__(16) u16 Bs[128][32];
    const int bx = blockIdx.x;
    if (bx < 6144) {
        long id = (long)bx * 256 + threadIdx.x;
        int seg = (int)(id >> 19);
        long e = (id & 524287L) * 8;
        const float* s = seg == 0 ? Q : (seg == 1 ? K : V);
        u16* d = seg == 0 ? Qb : (seg == 1 ? Kb : Vb);
        float4 lo = *(const float4*)(s + e);
        float4 hi = *(const float4*)(s + e + 4);
        u16x8 r;
        r[0]=f2bf(lo.x); r[1]=f2bf(lo.y); r[2]=f2bf(lo.z); r[3]=f2bf(lo.w);
        r[4]=f2bf(hi.x); r[5]=f2bf(hi.y); r[6]=f2bf(hi.z); r[7]=f2bf(hi.w);
        *(u16x8*)(d + e) = r;
        return;
    }
    const int bid = bx - 6144;                            // 0..15
    const int m0 = (bid & 3) * 128, n0 = (bid >> 2) * 128;
    const int t = threadIdx.x;
    f32x4 acc[4][4];
    #pragma unroll
    for (int i = 0; i < 4; i++)
        #pragma unroll
        for (int j = 0; j < 4; j++) acc[i][j] = (f32x4){0.f, 0.f, 0.f, 0.f};
    gemm_core(Wvb, Wst, 512, 512, 512, m0, n0, t, As, Bs, acc);
    gemm_epilogue(1, Wct, nullptr, 1.f, 512, m0, n0, t, acc);
}

// Fused attention: block = (16 q-rows, 1 batch). 4 waves.
// Phase 1 (QK): wave w owns kv strip [w*256, +256). Q A-frags preloaded to regs
//   (af[16], 64 VGPR); K B-frags read DIRECT from global (L2-resident, frag reads
//   fully consume 64B lines). acc[16] f32x4 = S strip in registers.
// Phase 2 (softmax): scale+mask in regs; row-max/sum via 4x shfl_xor within
//   16-lane quarter + cross-wave combine through tiny LDS. Exact (not online).
// Phase 3: att bf16 -> LDS S[16][1032] (pad 8 -> 2-way bank alias = free);
//   barrier; att f32 x8 slots stored fire-and-forget (drain under PV);
//   PV: A-frags from LDS, V B-frags direct from global; Y = att@Vwt^T + bl.
__global__ __launch_bounds__(256, 2)
void fused_attn(const u16* __restrict__ Qlb, const u16* __restrict__ Klb,
                const u16* __restrict__ Vwt, const int* __restrict__ mask,
                const float* __restrict__ bl,
                float* __restrict__ att, float* __restrict__ Yout)
{
    __shared__ u16 S[16][1032];          // bf16 att strip, padded
    __shared__ float redm[4][16];        // per-wave row max
    __shared__ float reds[4][16];        // per-wave row sum

    const int r0 = blockIdx.x * 16;      // q-row block
    const int b  = blockIdx.y;           // batch
    const int t  = threadIdx.x;
    const int w  = t >> 6, lane = t & 63;
    const int cl = lane & 15, q4 = lane >> 4;
    const int rl = q4 * 4;
    const int wkv = w * 256;             // phase-1 kv strip
    const int wn  = w * 128;             // phase-3 n strip
    const float isc = 0.04419417382415922f;   // 1/sqrt(512)

    const u16* Qb = Qlb + (long)b * 524288;
    const u16* Kb = Klb + (long)b * 524288;
    const u16* Vb = Vwt + (long)b * 524288;

    // ---- Phase 1: S = Q @ K^T (K=512, 16 k-steps, all in registers) ----
    bf16x8 af[16];
    #pragma unroll
    for (int ks = 0; ks < 16; ks++)
        af[ks] = *(const bf16x8*)(Qb + (long)(r0 + cl) * 512 + ks * 32 + q4 * 8);

    float mf[16];
    #pragma unroll
    for (int j = 0; j < 16; j++)
        mf[j] = (float)mask[b * 1024 + wkv + j * 16 + cl] * (-1e9f);

    f32x4 acc[16];
    #pragma unroll
    for (int j = 0; j < 16; j++) acc[j] = (f32x4){0.f, 0.f, 0.f, 0.f};

    #pragma unroll
    for (int ks = 0; ks < 16; ks++) {
        #pragma unroll
        for (int j = 0; j < 16; j++) {
            bf16x8 bf = *(const bf16x8*)(Kb + (long)(wkv + j * 16 + cl) * 512 + ks * 32 + q4 * 8);
            acc[j] = __builtin_amdgcn_mfma_f32_16x16x32_bf16(af[ks], bf, acc[j], 0, 0, 0);
        }
    }

    // scale + mask (C/D layout: col j*16+cl, row rl+r)
    #pragma unroll
    for (int j = 0; j < 16; j++)
        #pragma unroll
        for (int r = 0; r < 4; r++)
            acc[j][r] = acc[j][r] * isc + mf[j];

    // ---- Phase 2: exact softmax over 1024 cols ----
    float m[4];
    #pragma unroll
    for (int r = 0; r < 4; r++) {
        float v = acc[0][r];
        #pragma unroll
        for (int j = 1; j < 16; j++) v = fmaxf(v, acc[j][r]);
        #pragma unroll
        for (int o = 1; o < 16; o <<= 1) v = fmaxf(v, __shfl_xor(v, o));
        m[r] = v;
    }
    if (cl == 0) {
        #pragma unroll
        for (int r = 0; r < 4; r++) redm[w][rl + r] = m[r];
    }
    __syncthreads();
    #pragma unroll
    for (int r = 0; r < 4; r++)
        m[r] = fmaxf(fmaxf(redm[0][rl + r], redm[1][rl + r]),
                     fmaxf(redm[2][rl + r], redm[3][rl + r]));

    float sm[4] = {0.f, 0.f, 0.f, 0.f};
    #pragma unroll
    for (int j = 0; j < 16; j++)
        #pragma unroll
        for (int r = 0; r < 4; r++) {
            float e = __expf(acc[j][r] - m[r]);
            acc[j][r] = e;
            sm[r] += e;
        }
    #pragma unroll
    for (int r = 0; r < 4; r++)
        #pragma unroll
        for (int o = 1; o < 16; o <<= 1) sm[r] += __shfl_xor(sm[r], o);
    if (cl == 0) {
        #pragma unroll
        for (int r = 0; r < 4; r++) reds[w][rl + r] = sm[r];
    }
    __syncthreads();
    float inv[4];
    #pragma unroll
    for (int r = 0; r < 4; r++)
        inv[r] = 1.f / (reds[0][rl + r] + reds[1][rl + r] + reds[2][rl + r] + reds[3][rl + r]);

    // normalize; bf16 copy to LDS for PV
    #pragma unroll
    for (int j = 0; j < 16; j++)
        #pragma unroll
        for (int r = 0; r < 4; r++) {
            float a = acc[j][r] * inv[r];
            acc[j][r] = a;
            S[rl + r][wkv + j * 16 + cl] = f2bf(a);
        }
    __syncthreads();

    // att f32 x8 slots: fire-and-forget stores (drain under PV MFMAs)
    #pragma unroll
    for (int r = 0; r < 4; r++) {
        long base_r = (((long)b * 8) * 1024 + (r0 + rl + r)) * 1024 + wkv + cl;
        #pragma unroll
        for (int h = 0; h < 8; h++) {
            float* p = att + base_r + (long)h * 1048576;
            #pragma unroll
            for (int j = 0; j < 16; j++) p[j * 16] = acc[j][r];
        }
    }

    // ---- Phase 3: Y = att @ Vwt^T + bl (K=1024, 32 k-steps) ----
    f32x4 acc2[8];
    #pragma unroll
    for (int j = 0; j < 8; j++) acc2[j] = (f32x4){0.f, 0.f, 0.f, 0.f};

    #pragma unroll
    for (int ks = 0; ks < 32; ks++) {
        bf16x8 afv = *(const bf16x8*)&S[cl][ks * 32 + q4 * 8];
        #pragma unroll
        for (int j = 0; j < 8; j++) {
            bf16x8 bf = *(const bf16x8*)(Vb + (long)(wn + j * 16 + cl) * 1024 + ks * 32 + q4 * 8);
            acc2[j] = __builtin_amdgcn_mfma_f32_16x16x32_bf16(afv, bf, acc2[j], 0, 0, 0);
        }
    }

    float blv[8];
    #pragma unroll
    for (int j = 0; j < 8; j++) blv[j] = bl[wn + j * 16 + cl];
    #pragma unroll
    for (int r = 0; r < 4; r++) {
        float* yrow = Yout + (long)b * 524288 + (long)(r0 + rl + r) * 512;
        #pragma unroll
        for (int j = 0; j < 8; j++)
            yrow[wn + j * 16 + cl] = acc2[j][r] + blv[j];
    }
}

extern "C" void kernel_launch(void* const* d_in, const int* in_sizes, int n_in,
                              void* d_out, int out_size, void* d_ws, size_t ws_size,
                              hipStream_t stream)
{
    (void)in_sizes; (void)n_in; (void)out_size; (void)ws_size;

    const float* Q    = (const float*)d_in[0];
    const float* Kin  = (const float*)d_in[1];
    const float* V    = (const float*)d_in[2];
    const int*   mask = (const int*)d_in[3];
    const float* Wq   = (const float*)d_in[4];
    const float* bq   = (const float*)d_in[5];
    const float* Wk   = (const float*)d_in[6];
    const float* bk   = (const float*)d_in[7];
    const float* Wv   = (const float*)d_in[8];
    const float* bv   = (const float*)d_in[9];
    const float* Wl   = (const float*)d_in[10];
    const float* bl   = (const float*)d_in[11];

    float* out  = (float*)d_out;
    float* Yout = out;                            // [8,1024,512] f32
    float* att  = out + 4194304L;                 // [8,8,1024,1024] f32

    u16*   w    = (u16*)d_ws;
    float* bvs  = (float*)w;                      // 512 f32 (1024 u16)
    u16*   Qb   = w + 1024;
    u16*   Kb   = Qb + 4194304L;
    u16*   Vb   = Kb + 4194304L;
    u16*   Wqt  = Vb + 4194304L;
    u16*   Wkt  = Wqt + 262144L;
    u16*   Wvb  = Wkt + 262144L;
    u16*   Wst  = Wvb + 262144L;
    u16*   Wct  = Wst + 262144L;
    u16*   Qlb  = Wct + 262144L;
    u16*   Klb  = Qlb + 4194304L;
    u16*   Vwt  = Klb + 4194304L;                 // [b][512][1024]

    prep_w<<<dim3(4098), dim3(256), 0, stream>>>(Wq, Wk, Wv, Wl, bv,
                                                 Wqt, Wkt, Wvb, Wst, bvs);

    prep_qkv_wct<<<dim3(6160), dim3(256), 0, stream>>>(Q, Kin, V, Qb, Kb, Vb,
                                                       Wvb, Wst, Wct);

    gemm_qkvv<<<dim3(8, 4, 24), dim3(256), 0, stream>>>(
        Qb, Kb, Vb, Wqt, Wkt, Wct, Qlb, Klb, Vwt, bq, bk, bvs);

    fused_attn<<<dim3(64, 8), dim3(256), 0, stream>>>(
        Qlb, Klb, Vwt, mask, bl, att, Yout);
}

// Round 4
// 516.435 us; speedup vs baseline: 1.1208x; 1.1208x over previous
//
#include <hip/hip_runtime.h>
#include <stdint.h>

// MultiHeadAttention_62766652064333: DM=512 H=8 B=8 SQ=SK=1024. f32 I/O, int32 mask.
// v5: revert to staged trio (scores GEMM + softmax + Y GEMM, proven ~105us) and
// eliminate the K-projection via Wqk = Wq@Wk^T:
//   scores = Ql@Kl^T = Q@Wqk@K^T + u[m] + v[n] + bq.bk
//   where u = Q@(Wq bk), v = K@(Wk bq)   (exactly zero here, computed anyway)
// Y path unchanged from v3/v4: Y = att@(Vb@(Wv@Wsum)) + bvs + bl.
//
// Launches (6):
//   prep_w:        Wq,Wk,Wv bf16 straight; Wst=(sum_h Wl)^T bf16; bvs; wqbk,wkbq,c0
//   prep_qkv_wct:  Q,K,V f32->bf16 (6144) + Wqkt GEMM (16) + Wct GEMM (16) + u (16) + v (16)
//   gemm_tv:       z=0..7  T1 = Qb@Wqkt^T (bf16)   z=8..15 Vwt = (Vb@Wct^T + bvs)^T
//   gemm scores:   Sb = bf16(T1@Kb^T*isc + mask*(-1e9) + u[m] + v[n])
//   softmax_rep:   Sb -> f32 att x8 slots (d_out) + bf16 attb
//   gemm Y:        Yout = attb@Vwt^T + bl (f32)

typedef unsigned short u16;
typedef __attribute__((ext_vector_type(8))) short bf16x8;        // MFMA A/B frag
typedef __attribute__((ext_vector_type(8))) unsigned short u16x8;
typedef __attribute__((ext_vector_type(4))) unsigned short u16x4;
typedef __attribute__((ext_vector_type(4))) float f32x4;         // MFMA C/D frag

__device__ __forceinline__ u16 f2bf(float f) {
    union { float f; unsigned int u; } v; v.f = f;
    v.u += 0x7fffu + ((v.u >> 16) & 1u);   // round-to-nearest-even
    return (u16)(v.u >> 16);
}
__device__ __forceinline__ float bf2f(u16 u) {
    union { unsigned int u; float f; } v; v.u = (unsigned int)u << 16;
    return v.f;
}

__device__ __forceinline__ void gld16(const u16* g, u16* l) {
#if __has_builtin(__builtin_amdgcn_global_load_lds)
    __builtin_amdgcn_global_load_lds(
        (const __attribute__((address_space(1))) void*)g,
        (__attribute__((address_space(3))) void*)l, 16, 0, 0);
#else
    *(uint4*)l = *(const uint4*)g;
#endif
}

// ---- shared TN GEMM core: acc[4][4] += A[m0..+128, :] @ B[n0..+128, :]^T ----
// A[M,K], B[N,K] row-major bf16; K%32==0; rows 16B-aligned. m97 structure.
__device__ __forceinline__ void gemm_core(
    const u16* __restrict__ Ab, const u16* __restrict__ Bb,
    int K, int lda, int ldb, int m0, int n0, int t,
    u16 (*As)[32], u16 (*Bs)[32], f32x4 acc[4][4])
{
    const int lane = t & 63;
    const int wm = ((t >> 6) & 1) * 64;
    const int wn = (t >> 7) * 64;
    const int sr = t >> 2, sc = (t & 3) * 8;
    const int fr = lane & 15, fk = (lane >> 4) * 8;

    for (int k0 = 0; k0 < K; k0 += 32) {
        const u16* ap = Ab + (long)(m0 + sr) * lda + (k0 + sc);
        const u16* bp = Bb + (long)(n0 + sr) * ldb + (k0 + sc);
        gld16(ap,             &As[sr][sc]);
        gld16(ap + 64L * lda, &As[sr + 64][sc]);
        gld16(bp,             &Bs[sr][sc]);
        gld16(bp + 64L * ldb, &Bs[sr + 64][sc]);
        __syncthreads();

        bf16x8 af[4], bfv[4];
        #pragma unroll
        for (int i = 0; i < 4; i++) af[i]  = *(const bf16x8*)&As[wm + i*16 + fr][fk];
        #pragma unroll
        for (int j = 0; j < 4; j++) bfv[j] = *(const bf16x8*)&Bs[wn + j*16 + fr][fk];
        #pragma unroll
        for (int i = 0; i < 4; i++)
            #pragma unroll
            for (int j = 0; j < 4; j++)
                acc[i][j] = __builtin_amdgcn_mfma_f32_16x16x32_bf16(af[i], bfv[j], acc[i][j], 0, 0, 0);
        __syncthreads();
    }
}

// Epilogue: value = acc*scale + bias[col] + mask[col]*(-1e9) + urow[row] + vcol[col]
// mode 0: bf16 row-major.  mode 1: bf16 transposed (C[col*ldc+row]).  mode 2: f32 row-major.
// C/D frag layout: col = lane&15, row = (lane>>4)*4 + r   [HW-verified m89/m91]
__device__ __forceinline__ void gemm_epilogue(
    int mode, void* Cv, const float* bias, const int* maskp,
    const float* urow, const float* vcol,
    float scale, int ldc, int m0, int n0, int t, f32x4 acc[4][4])
{
    const int lane = t & 63;
    const int wm = ((t >> 6) & 1) * 64;
    const int wn = (t >> 7) * 64;
    const int cl = lane & 15, rl = (lane >> 4) * 4;

    float badd[4];
    #pragma unroll
    for (int j = 0; j < 4; j++) {
        int col = n0 + wn + j * 16 + cl;
        float v = bias ? bias[col] : 0.f;
        if (maskp) v += (float)maskp[col] * (-1e9f);
        if (vcol)  v += vcol[col];
        badd[j] = v;
    }

    if (mode == 1) {
        u16* C = (u16*)Cv;
        #pragma unroll
        for (int i = 0; i < 4; i++)
            #pragma unroll
            for (int r = 0; r < 4; r++) {
                long row = m0 + wm + i * 16 + rl + r;
                float ua = urow ? urow[row] : 0.f;
                #pragma unroll
                for (int j = 0; j < 4; j++)
                    C[(long)(n0 + wn + j * 16 + cl) * ldc + row] =
                        f2bf(acc[i][j][r] * scale + badd[j] + ua);
            }
    } else if (mode == 2) {
        float* C = (float*)Cv;
        #pragma unroll
        for (int i = 0; i < 4; i++)
            #pragma unroll
            for (int r = 0; r < 4; r++) {
                int row = m0 + wm + i * 16 + rl + r;
                float ua = urow ? urow[row] : 0.f;
                float* crow = C + (long)row * ldc;
                #pragma unroll
                for (int j = 0; j < 4; j++)
                    crow[n0 + wn + j * 16 + cl] = acc[i][j][r] * scale + badd[j] + ua;
            }
    } else {
        u16* C = (u16*)Cv;
        #pragma unroll
        for (int i = 0; i < 4; i++)
            #pragma unroll
            for (int r = 0; r < 4; r++) {
                int row = m0 + wm + i * 16 + rl + r;
                float ua = urow ? urow[row] : 0.f;
                u16* crow = C + (long)row * ldc;
                #pragma unroll
                for (int j = 0; j < 4; j++)
                    crow[n0 + wn + j * 16 + cl] = f2bf(acc[i][j][r] * scale + badd[j] + ua);
            }
    }
}

// Generic batched TN GEMM. sC in elements of the C type. urow/vcol per-batch stride 1024.
__global__ __launch_bounds__(256, 2)
void gemm_tn(const u16* __restrict__ A, const u16* __restrict__ B, void* __restrict__ Cv,
             const float* __restrict__ bias, const int* __restrict__ mask,
             const float* __restrict__ u, const float* __restrict__ v,
             int K, int lda, int ldb, int ldc,
             long sA, long sB, long sC, long sMask, float scale, int mode)
{
    __shared__ __align__(16) u16 As[128][32];
    __shared__ __align__(16) u16 Bs[128][32];
    const int bz = blockIdx.z;
    const int m0 = blockIdx.x * 128, n0 = blockIdx.y * 128;
    const int t = threadIdx.x;

    f32x4 acc[4][4];
    #pragma unroll
    for (int i = 0; i < 4; i++)
        #pragma unroll
        for (int j = 0; j < 4; j++) acc[i][j] = (f32x4){0.f, 0.f, 0.f, 0.f};

    gemm_core(A + (long)bz * sA, B + (long)bz * sB, K, lda, ldb, m0, n0, t, As, Bs, acc);

    void* Cb = (mode == 2) ? (void*)((float*)Cv + (long)bz * sC)
                           : (void*)((u16*)Cv + (long)bz * sC);
    const int* maskp = mask ? mask + (long)bz * sMask : nullptr;
    const float* up = u ? u + (long)bz * 1024 : nullptr;
    const float* vp = v ? v + (long)bz * 1024 : nullptr;
    gemm_epilogue(mode, Cb, bias, maskp, up, vp, scale, ldc, m0, n0, t, acc);
}

// T1 + Vw in one launch: grid (8,4,16). z 0..7: T1 = Qb@Wqkt^T (mode0, no bias).
// z 8..15: Vwt = (Vb@Wct^T + bvs)^T (mode1).
__global__ __launch_bounds__(256, 2)
void gemm_tv(const u16* __restrict__ Qb, const u16* __restrict__ Vb,
             const u16* __restrict__ Wqkt, const u16* __restrict__ Wct,
             u16* __restrict__ T1b, u16* __restrict__ Vwt,
             const float* __restrict__ bvs)
{
    __shared__ __align__(16) u16 As[128][32];
    __shared__ __align__(16) u16 Bs[128][32];
    const int z = blockIdx.z, seg = z >> 3, b = z & 7;
    const int m0 = blockIdx.x * 128, n0 = blockIdx.y * 128;
    const int t = threadIdx.x;
    const long sQ = 524288L;

    f32x4 acc[4][4];
    #pragma unroll
    for (int i = 0; i < 4; i++)
        #pragma unroll
        for (int j = 0; j < 4; j++) acc[i][j] = (f32x4){0.f, 0.f, 0.f, 0.f};

    if (seg == 0) {
        gemm_core(Qb + b * sQ, Wqkt, 512, 512, 512, m0, n0, t, As, Bs, acc);
        gemm_epilogue(0, T1b + b * sQ, nullptr, nullptr, nullptr, nullptr,
                      1.f, 512, m0, n0, t, acc);
    } else {
        gemm_core(Vb + b * sQ, Wct, 512, 512, 512, m0, n0, t, As, Bs, acc);
        gemm_epilogue(1, Vwt + b * sQ, bvs, nullptr, nullptr, nullptr,
                      1.f, 1024, m0, n0, t, acc);
    }
}

// Prep weights.
// blocks 0..4095: seg0 Wqb=bf16(Wq), seg1 Wkb=bf16(Wk), seg2 Wvb=bf16(Wv) (straight,
//   coalesced), seg3 Wst[n][k]=bf16(sum_h Wl[h][k][n]).
// blocks 4096..4097: bvs[n] = sum_k bv[k]*Wsum[k][n]  (zero-skip; exact).
// blocks 4098..4099: wqbk[i]=Wq[i,:].bk, wkbq[i]=Wk[i,:].bq; thread0 of 4098: c0=bq.bk.
__global__ __launch_bounds__(256)
void prep_w(const float* __restrict__ Wq, const float* __restrict__ Wk,
            const float* __restrict__ Wv, const float* __restrict__ Wl,
            const float* __restrict__ bq, const float* __restrict__ bk,
            const float* __restrict__ bv,
            u16* __restrict__ Wqb, u16* __restrict__ Wkb,
            u16* __restrict__ Wvb, u16* __restrict__ Wst,
            float* __restrict__ bvs, float* __restrict__ wqbk,
            float* __restrict__ wkbq, float* __restrict__ c0)
{
    const int bx = blockIdx.x;
    const int t  = threadIdx.x;
    if (bx >= 4098) {
        int i = (bx - 4098) * 256 + t;                    // 0..511
        float sq = 0.f, sk = 0.f;
        for (int o = 0; o < 512; o++) {
            sq += Wq[(long)i * 512 + o] * bk[o];
            sk += Wk[(long)i * 512 + o] * bq[o];
        }
        wqbk[i] = sq;
        wkbq[i] = sk;
        if (bx == 4098 && t == 0) {
            float s = 0.f;
            for (int o = 0; o < 512; o++) s += bq[o] * bk[o];
            c0[0] = s;
        }
        return;
    }
    if (bx >= 4096) {
        int n = (bx - 4096) * 256 + t;                    // 0..511
        float acc = 0.f;
        for (int k = 0; k < 512; k++) {
            float bvk = bv[k];
            if (bvk != 0.f) {
                float s = 0.f;
                #pragma unroll
                for (int h = 0; h < 8; h++) s += Wl[((long)h * 512 + k) * 512 + n];
                acc += bvk * s;
            }
        }
        bvs[n] = acc;
        return;
    }
    long id = (long)bx * 256 + t;                         // < 1048576
    int seg = (int)(id >> 18);
    long j = id & 262143L;
    if (seg == 0)      Wqb[j] = f2bf(Wq[j]);
    else if (seg == 1) Wkb[j] = f2bf(Wk[j]);
    else if (seg == 2) Wvb[j] = f2bf(Wv[j]);
    else {
        int n = (int)(j & 511), k = (int)(j >> 9);
        float s = 0.f;
        #pragma unroll
        for (int h = 0; h < 8; h++) s += Wl[((long)h * 512 + k) * 512 + n];
        Wst[(long)n * 512 + k] = f2bf(s);
    }
}

// blocks 0..6143: Q,K,V f32->bf16.
// blocks 6144..6159: Wqkt = (Wqb@Wkb^T)^T  (TN mode1) -> B-operand for T1.
// blocks 6160..6175: Wct  = (Wvb@Wst^T)^T  (TN mode1) -> B-operand for Vw.
// blocks 6176..6191: u[m] = Q[m,:].wqbk + c0   (16 blocks x 4 waves x 128 rows)
// blocks 6192..6207: v[m] = K[m,:].wkbq
__global__ __launch_bounds__(256, 2)
void prep_qkv_wct(const float* __restrict__ Q, const float* __restrict__ K,
                  const float* __restrict__ V, u16* __restrict__ Qb,
                  u16* __restrict__ Kb, u16* __restrict__ Vb,
                  const u16* __restrict__ Wqb, const u16* __restrict__ Wkb,
                  const u16* __restrict__ Wvb, const u16* __restrict__ Wst,
                  u16* __restrict__ Wqkt, u16* __restrict__ Wct,
                  const float* __restrict__ wqbk, const float* __restrict__ wkbq,
                  const float* __restrict__ c0,
                  float* __restrict__ u, float* __restrict__ v)
{
    __shared__ __align__(16) u16 As[128][32];
    __shared__ __align__(16) u16 Bs[128][32];
    const int bx = blockIdx.x;
    const int t  = threadIdx.x;

    if (bx < 6144) {
        long id = (long)bx * 256 + t;
        int seg = (int)(id >> 19);
        long e = (id & 524287L) * 8;
        const float* s = seg == 0 ? Q : (seg == 1 ? K : V);
        u16* d = seg == 0 ? Qb : (seg == 1 ? Kb : Vb);
        float4 lo = *(const float4*)(s + e);
        float4 hi = *(const float4*)(s + e + 4);
        u16x8 r;
        r[0]=f2bf(lo.x); r[1]=f2bf(lo.y); r[2]=f2bf(lo.z); r[3]=f2bf(lo.w);
        r[4]=f2bf(hi.x); r[5]=f2bf(hi.y); r[6]=f2bf(hi.z); r[7]=f2bf(hi.w);
        *(u16x8*)(d + e) = r;
        return;
    }
    if (bx < 6176) {
        const int bid = bx - 6144;                        // 0..31
        const int which = bid >> 4;                       // 0: Wqkt, 1: Wct
        const int sub = bid & 15;
        const int m0 = (sub & 3) * 128, n0 = (sub >> 2) * 128;
        f32x4 acc[4][4];
        #pragma unroll
        for (int i = 0; i < 4; i++)
            #pragma unroll
            for (int j = 0; j < 4; j++) acc[i][j] = (f32x4){0.f, 0.f, 0.f, 0.f};
        if (which == 0) {
            gemm_core(Wqb, Wkb, 512, 512, 512, m0, n0, t, As, Bs, acc);
            gemm_epilogue(1, Wqkt, nullptr, nullptr, nullptr, nullptr,
                          1.f, 512, m0, n0, t, acc);
        } else {
            gemm_core(Wvb, Wst, 512, 512, 512, m0, n0, t, As, Bs, acc);
            gemm_epilogue(1, Wct, nullptr, nullptr, nullptr, nullptr,
                          1.f, 512, m0, n0, t, acc);
        }
        return;
    }
    // u / v matvecs: 16 blocks each; block covers 512 rows (4 waves x 128)
    {
        const int bid = bx - 6176;                        // 0..31
        const int isv = bid >> 4;                         // 0: u from Q, 1: v from K
        const int sub = bid & 15;
        const float* src = isv ? K : Q;
        const float* wvp = isv ? wkbq : wqbk;
        float* dst = isv ? v : u;
        const float cadd = isv ? 0.f : c0[0];

        __shared__ float wsh[512];
        wsh[t] = wvp[t];
        wsh[t + 256] = wvp[t + 256];
        __syncthreads();

        const int w = t >> 6, lane = t & 63;
        float wc0, wc1, wc2, wc3, wc4, wc5, wc6, wc7;
        {
            const float* p = &wsh[lane * 8];
            wc0=p[0]; wc1=p[1]; wc2=p[2]; wc3=p[3]; wc4=p[4]; wc5=p[5]; wc6=p[6]; wc7=p[7];
        }
        for (int r = 0; r < 128; r++) {
            long row = (long)sub * 512 + w * 128 + r;
            const float* p = src + row * 512 + lane * 8;
            float4 a = *(const float4*)p;
            float4 b2 = *(const float4*)(p + 4);
            float s = a.x*wc0 + a.y*wc1 + a.z*wc2 + a.w*wc3
                    + b2.x*wc4 + b2.y*wc5 + b2.z*wc6 + b2.w*wc7;
            #pragma unroll
            for (int o = 1; o < 64; o <<= 1) s += __shfl_xor(s, o);
            if (lane == 0) dst[row] = s + cadd;
        }
    }
}

// One block per (q,b): softmax of bf16 scores row; writes f32 att rows to all 8 slots
// of d_out AND a bf16 copy to attb (d_ws) for the Y GEMM.  [proven v3 kernel]
__global__ __launch_bounds__(256)
void softmax_rep(const u16* __restrict__ Sb, float* __restrict__ att,
                 u16* __restrict__ attb)
{
    const int q = blockIdx.x, b = blockIdx.y;
    const int t = threadIdx.x;
    const u16* row = Sb + ((long)b * 1024 + q) * 1024;

    u16x4 xv = *(const u16x4*)(row + t * 4);
    float x[4] = { bf2f(xv[0]), bf2f(xv[1]), bf2f(xv[2]), bf2f(xv[3]) };

    float m = fmaxf(fmaxf(x[0], x[1]), fmaxf(x[2], x[3]));
    #pragma unroll
    for (int o = 32; o > 0; o >>= 1) m = fmaxf(m, __shfl_xor(m, o));
    __shared__ float red[4];
    const int w = t >> 6;
    if ((t & 63) == 0) red[w] = m;
    __syncthreads();
    m = fmaxf(fmaxf(red[0], red[1]), fmaxf(red[2], red[3]));
    __syncthreads();

    float e[4], s = 0.f;
    #pragma unroll
    for (int i = 0; i < 4; i++) { e[i] = __expf(x[i] - m); s += e[i]; }
    #pragma unroll
    for (int o = 32; o > 0; o >>= 1) s += __shfl_xor(s, o);
    if ((t & 63) == 0) red[w] = s;
    __syncthreads();
    s = red[0] + red[1] + red[2] + red[3];
    float inv = 1.f / s;

    float a0 = e[0]*inv, a1 = e[1]*inv, a2 = e[2]*inv, a3 = e[3]*inv;
    float4 ov = make_float4(a0, a1, a2, a3);
    #pragma unroll
    for (int h = 0; h < 8; h++)
        *(float4*)(att + (((long)b * 8 + h) * 1024 + q) * 1024 + t * 4) = ov;
    u16x4 bo; bo[0]=f2bf(a0); bo[1]=f2bf(a1); bo[2]=f2bf(a2); bo[3]=f2bf(a3);
    *(u16x4*)(attb + ((long)b * 1024 + q) * 1024 + t * 4) = bo;
}

extern "C" void kernel_launch(void* const* d_in, const int* in_sizes, int n_in,
                              void* d_out, int out_size, void* d_ws, size_t ws_size,
                              hipStream_t stream)
{
    (void)in_sizes; (void)n_in; (void)out_size; (void)ws_size;

    const float* Q    = (const float*)d_in[0];
    const float* Kin  = (const float*)d_in[1];
    const float* V    = (const float*)d_in[2];
    const int*   mask = (const int*)d_in[3];
    const float* Wq   = (const float*)d_in[4];
    const float* bq   = (const float*)d_in[5];
    const float* Wk   = (const float*)d_in[6];
    const float* bk   = (const float*)d_in[7];
    const float* Wv   = (const float*)d_in[8];
    const float* bv   = (const float*)d_in[9];
    const float* Wl   = (const float*)d_in[10];
    const float* bl   = (const float*)d_in[11];

    float* out  = (float*)d_out;
    float* Yout = out;                            // [8,1024,512] f32
    float* att  = out + 4194304L;                 // [8,8,1024,1024] f32

    // scratch layout in d_ws (u16 units; ~76 MB total)
    u16*   w    = (u16*)d_ws;
    float* bvs  = (float*)w;                      // 512 f32
    float* wqbk = bvs + 512;                      // 512 f32
    float* wkbq = wqbk + 512;                     // 512 f32
    float* c0   = wkbq + 512;                     // 1 f32 (pad to 512)
    float* uvec = c0 + 512;                       // 8192 f32
    float* vvec = uvec + 8192;                    // 8192 f32
    u16*   Qb   = w + 2L * (512*4 + 8192*2);      // after 18944 f32 = 37888 u16
    u16*   Kb   = Qb + 4194304L;
    u16*   Vb   = Kb + 4194304L;
    u16*   Wqb  = Vb + 4194304L;                  // 262144 each
    u16*   Wkb  = Wqb + 262144L;
    u16*   Wvb  = Wkb + 262144L;
    u16*   Wst  = Wvb + 262144L;
    u16*   Wqkt = Wst + 262144L;
    u16*   Wct  = Wqkt + 262144L;
    u16*   T1b  = Wct + 262144L;                  // 4194304
    u16*   Vwt  = T1b + 4194304L;                 // [b][512][1024]
    u16*   Sb   = Vwt + 4194304L;                 // [b][1024][1024]
    u16*   attb = Sb + 8388608L;                  // [b][1024][1024]

    const long sQ  = 524288L;
    const long sAt = 1048576L;
    const float isc = 0.04419417382415922f;       // 1/sqrt(512)

    prep_w<<<dim3(4100), dim3(256), 0, stream>>>(
        Wq, Wk, Wv, Wl, bq, bk, bv, Wqb, Wkb, Wvb, Wst, bvs, wqbk, wkbq, c0);

    prep_qkv_wct<<<dim3(6208), dim3(256), 0, stream>>>(
        Q, Kin, V, Qb, Kb, Vb, Wqb, Wkb, Wvb, Wst, Wqkt, Wct,
        wqbk, wkbq, c0, uvec, vvec);

    // T1 + Vw: 512 blocks (~2/CU)
    gemm_tv<<<dim3(8, 4, 16), dim3(256), 0, stream>>>(
        Qb, Vb, Wqkt, Wct, T1b, Vwt, bvs);

    // Sb = bf16(T1@Kb^T*isc + mask*(-1e9) + u[m] + v[n]): M=N=1024 K=512, 512 blocks
    gemm_tn<<<dim3(8, 8, 8), dim3(256), 0, stream>>>(
        T1b, Kb, Sb, nullptr, mask, uvec, vvec, 512, 512, 512, 1024,
        sQ, sQ, sAt, 1024L, isc, 0);

    softmax_rep<<<dim3(1024, 8), dim3(256), 0, stream>>>(Sb, att, attb);

    // Y = attb@Vwt^T + bl (f32): M=1024 N=512 K=1024, 256 blocks
    gemm_tn<<<dim3(8, 4, 8), dim3(256), 0, stream>>>(
        attb, Vwt, Yout, bl, nullptr, nullptr, nullptr, 1024, 1024, 1024, 512,
        sAt, sQ, sQ, 0L, 1.f, 2);
}